// Round 1
// baseline (196.357 us; speedup 1.0000x reference)
//
#include <hip/hip_runtime.h>
#include <math.h>

#define B_ 2
#define T_ 2048
#define C_ 1024
#define H_ 16
#define D_ 64

typedef short short8 __attribute__((ext_vector_type(8)));
typedef float f32x4 __attribute__((ext_vector_type(4)));

#define LOG2E 1.44269504088896f

__device__ __forceinline__ unsigned short f2bf(float f) {
    unsigned int u = __float_as_uint(f);
    u += 0x7FFFu + ((u >> 16) & 1u);
    return (unsigned short)(u >> 16);
}

#define NCAST 2560   // (4M + 1M) / 2048 cast blocks

// ---------------------------------------------------------------------------
// Fused prep: blocks [0,NCAST) cast x|Wo fp32->bf16 (8 elems/thread);
// blocks [NCAST, NCAST+768) transpose Wq/Wk/Wv (H,C,D)->(H,D,C) bf16 into
// Wall^T slices. [r10 verified]
// ---------------------------------------------------------------------------
__global__ __launch_bounds__(256) void prep_all(
    const float* __restrict__ x,  const float* __restrict__ Wq,
    const float* __restrict__ Wk, const float* __restrict__ Wv,
    const float* __restrict__ Wo,
    unsigned short* __restrict__ xb,   unsigned short* __restrict__ Wall,
    unsigned short* __restrict__ wob,  int nX, int nW)
{
    const int bid = blockIdx.x;
    const int tid = threadIdx.x;
    if (bid < NCAST) {
        int i = (bid * 256 + tid) * 8;
        const float* s;
        unsigned short* d;
        if (i < nX) { s = x + i; d = xb + i; }
        else {
            int j = i - nX;
            if (j >= nW) return;
            s = Wo + j; d = wob + j;
        }
        float4 a = *(const float4*)s;
        float4 b = *(const float4*)(s + 4);
        ushort4 o0, o1;
        o0.x = f2bf(a.x); o0.y = f2bf(a.y); o0.z = f2bf(a.z); o0.w = f2bf(a.w);
        o1.x = f2bf(b.x); o1.y = f2bf(b.y); o1.z = f2bf(b.z); o1.w = f2bf(b.w);
        *(ushort4*)d = o0;
        *(ushort4*)(d + 4) = o1;
        return;
    }
    // transpose path
    __shared__ float t[64][65];
    const int tb = bid - NCAST;          // 0..767
    const int c0 = (tb & 15) * 64;
    const int h  = (tb >> 4) & 15;
    const int z  = tb >> 8;
    const float* W = (z == 0) ? Wq : (z == 1) ? Wk : Wv;
    unsigned short* Wt = Wall + (size_t)z * H_ * D_ * C_;
    const int r = tid >> 4, c4 = (tid & 15) * 4;
    #pragma unroll
    for (int p = 0; p < 4; p++) {
        int cl = r + p * 16;
        float4 v = *(const float4*)&W[((size_t)h * C_ + c0 + cl) * D_ + c4];
        t[cl][c4 + 0] = v.x; t[cl][c4 + 1] = v.y;
        t[cl][c4 + 2] = v.z; t[cl][c4 + 3] = v.w;
    }
    __syncthreads();
    #pragma unroll
    for (int p = 0; p < 4; p++) {
        int d = r + p * 16;
        ushort4 o;
        o.x = f2bf(t[c4 + 0][d]); o.y = f2bf(t[c4 + 1][d]);
        o.z = f2bf(t[c4 + 2][d]); o.w = f2bf(t[c4 + 3][d]);
        *(ushort4*)&Wt[((size_t)h * D_ + d) * C_ + c0 + c4] = o;
    }
}

// ---------------------------------------------------------------------------
// QKV GEMM (r8/r10 register-prefetch structure): xb bf16 (4096x1024) x
// Wall^T bf16 (3072x1024), 128x128 tiles. grid = (32, 24).
// z==0 -> Q (scaled 0.125*log2e), z==1 -> K, z==2 -> V^T (B,H,D,T) directly.
// ---------------------------------------------------------------------------
__global__ __launch_bounds__(256) void qkv_big(
    const unsigned short* __restrict__ X,
    const unsigned short* __restrict__ Wall,
    unsigned short* __restrict__ Qo,
    unsigned short* __restrict__ Ko,
    unsigned short* __restrict__ Vt)
{
    __shared__ unsigned short As[128][72];
    __shared__ unsigned short Bs[128][72];

    const int m0 = blockIdx.x * 128;
    const int n0 = blockIdx.y * 128;
    const int z  = n0 >> 10;
    const int tid = threadIdx.x;
    const int w = tid >> 6, lane = tid & 63, quad = lane >> 4, l16 = lane & 15;
    const int wm = w & 1, wn = w >> 1;
    const int lrow = tid >> 3, lcol = (tid & 7) * 8;

    f32x4 acc[4][4] = {};

    short8 ar[4], br[4];
    #pragma unroll
    for (int p = 0; p < 4; p++) {
        int r = lrow + p * 32;
        ar[p] = *(const short8*)&X[(size_t)(m0 + r) * C_ + lcol];
        br[p] = *(const short8*)&Wall[(size_t)(n0 + r) * C_ + lcol];
    }

    for (int k0 = 0; k0 < C_; k0 += 64) {
        __syncthreads();
        #pragma unroll
        for (int p = 0; p < 4; p++) {
            int r = lrow + p * 32;
            *(short8*)&As[r][lcol] = ar[p];
            *(short8*)&Bs[r][lcol] = br[p];
        }
        __syncthreads();
        if (k0 + 64 < C_) {
            #pragma unroll
            for (int p = 0; p < 4; p++) {
                int r = lrow + p * 32;
                ar[p] = *(const short8*)&X[(size_t)(m0 + r) * C_ + k0 + 64 + lcol];
                br[p] = *(const short8*)&Wall[(size_t)(n0 + r) * C_ + k0 + 64 + lcol];
            }
        }
        #pragma unroll
        for (int ks = 0; ks < 2; ks++) {
            short8 af[4], bf[4];
            #pragma unroll
            for (int i = 0; i < 4; i++)
                af[i] = *(const short8*)&As[wm * 64 + i * 16 + l16][ks * 32 + quad * 8];
            #pragma unroll
            for (int j = 0; j < 4; j++)
                bf[j] = *(const short8*)&Bs[wn * 64 + j * 16 + l16][ks * 32 + quad * 8];
            #pragma unroll
            for (int i = 0; i < 4; i++)
                #pragma unroll
                for (int j = 0; j < 4; j++)
                    acc[i][j] = __builtin_amdgcn_mfma_f32_16x16x32_bf16(af[i], bf[j], acc[i][j], 0, 0, 0);
        }
    }

    if (z == 2) {
        // V^T epilogue: Vt[b,h,d,t], 4 consecutive t per (i,j) -> 8B stores
        #pragma unroll
        for (int j = 0; j < 4; j++) {
            const int n = n0 + wn * 64 + j * 16 + l16;
            const int h = (n >> 6) & 15, d = n & 63;
            #pragma unroll
            for (int i = 0; i < 4; i++) {
                const int m = m0 + wm * 64 + i * 16 + quad * 4;
                const int b = m >> 11, t = m & (T_ - 1);
                ushort4 pk;
                pk.x = f2bf(acc[i][j][0]);
                pk.y = f2bf(acc[i][j][1]);
                pk.z = f2bf(acc[i][j][2]);
                pk.w = f2bf(acc[i][j][3]);
                *(ushort4*)&Vt[(((size_t)b * H_ + h) * D_ + d) * T_ + t] = pk;
            }
        }
    } else {
        const float scale = (z == 0) ? 0.125f * LOG2E : 1.0f;
        unsigned short* O = (z == 0) ? Qo : Ko;
        #pragma unroll
        for (int j = 0; j < 4; j++) {
            const int n = n0 + wn * 64 + j * 16 + l16;
            const int h = (n >> 6) & 15, d = n & 63;
            #pragma unroll
            for (int i = 0; i < 4; i++)
                #pragma unroll
                for (int r = 0; r < 4; r++) {
                    const int m = m0 + wm * 64 + i * 16 + quad * 4 + r;
                    const int b = m >> 11, t = m & (T_ - 1);
                    O[(((size_t)b * H_ + h) * T_ + t) * D_ + d] = f2bf(acc[i][j][r] * scale);
                }
        }
    }
}

// ---------------------------------------------------------------------------
// Flash attention (causal), no-max exp2 softmax. r11 restructure:
//  - 256-thread blocks (4 waves), ONE qb per block, no intra-block K-split:
//    no 8-wave lockstep barriers, no group-combine LDS round-trip.
//    grid = 1024 blocks -> 4 blocks/CU (LDS 27.9KB), occupancy 33% -> ~50%.
//  - XCD-contiguous remap: blockIdx.x d -> W=(d&7)*128+(d>>3); each XCD owns
//    4 whole heads (2MB K/V < 4MB L2) -> kills the 4x HBM over-fetch.
//  - s_setprio(1) around both MFMA clusters (T5, m191: +4-7% attn).
// S' = K·Q^T layout (swapped operands) retained: lane holds P at
// (s=ct*16+quad*4+r, q=w*16+l16); P -> ps via packed b64; PV A-frag b128.
// ---------------------------------------------------------------------------
__global__ __launch_bounds__(256, 4) void flash_mfma(
    const unsigned short* __restrict__ Q,
    const unsigned short* __restrict__ K,
    const unsigned short* __restrict__ Vt,   // (B,H,D,T)
    unsigned short* __restrict__ CC)         // (B,T,C)
{
    __shared__ unsigned short kst[64][72];   // K tile [s][d]
    __shared__ unsigned short vts[64][72];   // V^T tile [d][s]
    __shared__ unsigned short ps [64][72];   // P tile [q][s]
    __shared__ float flb[64];                // l broadcast (per-wave 16 slots)

    const int dd = blockIdx.x;               // 0..1023
    const int W  = (dd & 7) * 128 + (dd >> 3);   // XCD-contiguous (bijective)
    const int qb = W & 31;
    const int head = W >> 5;                 // 0..31, 4 consecutive per XCD
    const int h = head & 15, b = head >> 4;

    const int tid = threadIdx.x;
    const int w = tid >> 6, lane = tid & 63, quad = lane >> 4, l16 = lane & 15;
    const int lrow = tid >> 3, lcol = (tid & 7) * 8;
    const size_t hb  = ((size_t)b * H_ + h) * T_;
    const size_t hbD = ((size_t)b * H_ + h) * D_;
    const int q0 = qb * 64;
    const int nkb = qb + 1;

    short8 qf[2];
    #pragma unroll
    for (int ks = 0; ks < 2; ks++)
        qf[ks] = *(const short8*)&Q[(hb + q0 + w * 16 + l16) * D_ + ks * 32 + quad * 8];

    float l_lane = 0.0f;   // l partial for q = w*16 + l16
    f32x4 o[4] = {};

    short8 kreg[2], vreg[2];
    #pragma unroll
    for (int p = 0; p < 2; p++) {
        int r = lrow + p * 32;
        kreg[p] = *(const short8*)&K[(hb + r) * D_ + lcol];
        vreg[p] = *(const short8*)&Vt[(hbD + r) * T_ + lcol];
    }

    for (int kb = 0; kb < nkb; kb++) {
        __syncthreads();
        #pragma unroll
        for (int p = 0; p < 2; p++) {
            int r = lrow + p * 32;
            *(short8*)&kst[r][lcol] = kreg[p];
            *(short8*)&vts[r][lcol] = vreg[p];
        }
        __syncthreads();
        if (kb + 1 < nkb) {
            const int k0n = (kb + 1) * 64;
            #pragma unroll
            for (int p = 0; p < 2; p++) {
                int r = lrow + p * 32;
                kreg[p] = *(const short8*)&K[(hb + k0n + r) * D_ + lcol];
                vreg[p] = *(const short8*)&Vt[(hbD + r) * T_ + k0n + lcol];
            }
        }

        // S' = K Q^T: lane holds s = ct*16 + quad*4 + r, q = w*16 + l16
        f32x4 s[4] = {};
        __builtin_amdgcn_s_setprio(1);
        #pragma unroll
        for (int ks = 0; ks < 2; ks++)
            #pragma unroll
            for (int ct = 0; ct < 4; ct++) {
                short8 kf = *(const short8*)&kst[ct * 16 + l16][ks * 32 + quad * 8];
                s[ct] = __builtin_amdgcn_mfma_f32_16x16x32_bf16(kf, qf[ks], s[ct], 0, 0, 0);
            }
        __builtin_amdgcn_s_setprio(0);

        if (kb == qb) {   // diagonal block: mask s > q (local indices)
            #pragma unroll
            for (int ct = 0; ct < 4; ct++)
                #pragma unroll
                for (int r = 0; r < 4; r++)
                    if (ct * 16 + quad * 4 + r > w * 16 + l16) s[ct][r] = -INFINITY;
        }

        // P = exp2(S'); pack pairs to bf16 (round-half-up) -> b64 store
        #pragma unroll
        for (int ct = 0; ct < 4; ct++) {
            float e0 = exp2f(s[ct][0]);
            float e1 = exp2f(s[ct][1]);
            float e2 = exp2f(s[ct][2]);
            float e3 = exp2f(s[ct][3]);
            l_lane += (e0 + e1) + (e2 + e3);
            uint2 pk;
            pk.x = __builtin_amdgcn_perm(
                __float_as_uint(e1) + 0x8000u, __float_as_uint(e0) + 0x8000u, 0x07060302u);
            pk.y = __builtin_amdgcn_perm(
                __float_as_uint(e3) + 0x8000u, __float_as_uint(e2) + 0x8000u, 0x07060302u);
            *(uint2*)&ps[w * 16 + l16][ct * 16 + quad * 4] = pk;
        }

        // O += P V (ps rows wave-private; same-wave DS ordering, no barrier)
        __builtin_amdgcn_s_setprio(1);
        #pragma unroll
        for (int ks = 0; ks < 2; ks++) {
            short8 pa = *(const short8*)&ps[w * 16 + l16][ks * 32 + quad * 8];
            #pragma unroll
            for (int ct = 0; ct < 4; ct++) {
                short8 vf = *(const short8*)&vts[ct * 16 + l16][ks * 32 + quad * 8];
                o[ct] = __builtin_amdgcn_mfma_f32_16x16x32_bf16(pa, vf, o[ct], 0, 0, 0);
            }
        }
        __builtin_amdgcn_s_setprio(0);
    }

    // total l per q: reduce across quads (lanes sharing l16)
    l_lane += __shfl_xor(l_lane, 16);
    l_lane += __shfl_xor(l_lane, 32);
    if (lane < 16) flb[w * 16 + lane] = l_lane;   // wave-private transpose
    #pragma unroll
    for (int r = 0; r < 4; r++) {
        const int q = w * 16 + quad * 4 + r;
        const float invl = 1.0f / flb[q];
        const int t = q0 + q;
        #pragma unroll
        for (int ct = 0; ct < 4; ct++)
            CC[((size_t)b * T_ + t) * C_ + h * D_ + ct * 16 + l16] = f2bf(o[ct][r] * invl);
    }
}

// ---------------------------------------------------------------------------
// Output projection (r8/r10 structure): out[m,n] = sum_c CC[m,c] * Wo[n,c],
// 128x128 tiles, register-prefetched. grid = (32, 8). fp32 output.
// ---------------------------------------------------------------------------
__global__ __launch_bounds__(256) void out_big(
    const unsigned short* __restrict__ X,
    const unsigned short* __restrict__ Wob,
    float* __restrict__ out)
{
    __shared__ unsigned short As[128][72];
    __shared__ unsigned short Bs[128][72];

    const int m0 = blockIdx.x * 128;
    const int n0 = blockIdx.y * 128;
    const int tid = threadIdx.x;
    const int w = tid >> 6, lane = tid & 63, quad = lane >> 4, l16 = lane & 15;
    const int wm = w & 1, wn = w >> 1;
    const int lrow = tid >> 3, lcol = (tid & 7) * 8;

    f32x4 acc[4][4] = {};

    short8 ar[4], br[4];
    #pragma unroll
    for (int p = 0; p < 4; p++) {
        int r = lrow + p * 32;
        ar[p] = *(const short8*)&X[(size_t)(m0 + r) * C_ + lcol];
        br[p] = *(const short8*)&Wob[(size_t)(n0 + r) * C_ + lcol];
    }

    for (int k0 = 0; k0 < C_; k0 += 64) {
        __syncthreads();
        #pragma unroll
        for (int p = 0; p < 4; p++) {
            int r = lrow + p * 32;
            *(short8*)&As[r][lcol] = ar[p];
            *(short8*)&Bs[r][lcol] = br[p];
        }
        __syncthreads();
        if (k0 + 64 < C_) {
            #pragma unroll
            for (int p = 0; p < 4; p++) {
                int r = lrow + p * 32;
                ar[p] = *(const short8*)&X[(size_t)(m0 + r) * C_ + k0 + 64 + lcol];
                br[p] = *(const short8*)&Wob[(size_t)(n0 + r) * C_ + k0 + 64 + lcol];
            }
        }
        #pragma unroll
        for (int ks = 0; ks < 2; ks++) {
            short8 af[4], bf[4];
            #pragma unroll
            for (int i = 0; i < 4; i++)
                af[i] = *(const short8*)&As[wm * 64 + i * 16 + l16][ks * 32 + quad * 8];
            #pragma unroll
            for (int j = 0; j < 4; j++)
                bf[j] = *(const short8*)&Bs[wn * 64 + j * 16 + l16][ks * 32 + quad * 8];
            #pragma unroll
            for (int i = 0; i < 4; i++)
                #pragma unroll
                for (int j = 0; j < 4; j++)
                    acc[i][j] = __builtin_amdgcn_mfma_f32_16x16x32_bf16(af[i], bf[j], acc[i][j], 0, 0, 0);
        }
    }

    #pragma unroll
    for (int i = 0; i < 4; i++)
        #pragma unroll
        for (int j = 0; j < 4; j++)
            #pragma unroll
            for (int r = 0; r < 4; r++)
                out[(size_t)(m0 + wm * 64 + i * 16 + quad * 4 + r) * C_ + n0 + wn * 64 + j * 16 + l16] = acc[i][j][r];
}

extern "C" void kernel_launch(void* const* d_in, const int* in_sizes, int n_in,
                              void* d_out, int out_size, void* d_ws, size_t ws_size,
                              hipStream_t stream) {
    const float* x  = (const float*)d_in[0];
    const float* Wq = (const float*)d_in[1];
    const float* Wk = (const float*)d_in[2];
    const float* Wv = (const float*)d_in[3];
    const float* Wo = (const float*)d_in[4];
    float* out = (float*)d_out;

    const size_t nX = (size_t)B_ * T_ * C_;      // 4M
    const size_t nW = (size_t)H_ * C_ * D_;      // 1M per z
    const size_t nQ = (size_t)B_ * H_ * T_ * D_; // 4M
    unsigned short* xb   = (unsigned short*)d_ws;
    unsigned short* Wall = xb + nX;
    unsigned short* Wob  = Wall + 3 * nW;
    unsigned short* Qb   = Wob + nW;
    unsigned short* Kb   = Qb + nQ;
    unsigned short* Vtb  = Kb + nQ;
    unsigned short* CCb  = Vtb + nQ;   // total 24M ushorts = 48 MB

    prep_all<<<dim3(NCAST + 768), 256, 0, stream>>>(
        x, Wq, Wk, Wv, Wo, xb, Wall, Wob, (int)nX, (int)nW);
    qkv_big<<<dim3(32, 24), 256, 0, stream>>>(xb, Wall, Qb, Kb, Vtb);
    flash_mfma<<<dim3(1024), 256, 0, stream>>>(Qb, Kb, Vtb, CCb);
    out_big<<<dim3(32, 8), 256, 0, stream>>>(CCb, Wob, out);
}

// Round 2
// 174.819 us; speedup vs baseline: 1.1232x; 1.1232x over previous
//
#include <hip/hip_runtime.h>
#include <math.h>

#define B_ 2
#define T_ 2048
#define C_ 1024
#define H_ 16
#define D_ 64

typedef short short8 __attribute__((ext_vector_type(8)));
typedef float f32x4 __attribute__((ext_vector_type(4)));

#define LOG2E 1.44269504088896f

__device__ __forceinline__ unsigned short f2bf(float f) {
    unsigned int u = __float_as_uint(f);
    u += 0x7FFFu + ((u >> 16) & 1u);
    return (unsigned short)(u >> 16);
}

#define NCAST 2560   // (4M + 1M) / 2048 cast blocks

// ---------------------------------------------------------------------------
// Fused prep: blocks [0,NCAST) cast x|Wo fp32->bf16 (8 elems/thread);
// blocks [NCAST, NCAST+768) transpose Wq/Wk/Wv (H,C,D)->(H,D,C) bf16 into
// Wall^T slices. [r10 verified]
// ---------------------------------------------------------------------------
__global__ __launch_bounds__(256) void prep_all(
    const float* __restrict__ x,  const float* __restrict__ Wq,
    const float* __restrict__ Wk, const float* __restrict__ Wv,
    const float* __restrict__ Wo,
    unsigned short* __restrict__ xb,   unsigned short* __restrict__ Wall,
    unsigned short* __restrict__ wob,  int nX, int nW)
{
    const int bid = blockIdx.x;
    const int tid = threadIdx.x;
    if (bid < NCAST) {
        int i = (bid * 256 + tid) * 8;
        const float* s;
        unsigned short* d;
        if (i < nX) { s = x + i; d = xb + i; }
        else {
            int j = i - nX;
            if (j >= nW) return;
            s = Wo + j; d = wob + j;
        }
        float4 a = *(const float4*)s;
        float4 b = *(const float4*)(s + 4);
        ushort4 o0, o1;
        o0.x = f2bf(a.x); o0.y = f2bf(a.y); o0.z = f2bf(a.z); o0.w = f2bf(a.w);
        o1.x = f2bf(b.x); o1.y = f2bf(b.y); o1.z = f2bf(b.z); o1.w = f2bf(b.w);
        *(ushort4*)d = o0;
        *(ushort4*)(d + 4) = o1;
        return;
    }
    // transpose path
    __shared__ float t[64][65];
    const int tb = bid - NCAST;          // 0..767
    const int c0 = (tb & 15) * 64;
    const int h  = (tb >> 4) & 15;
    const int z  = tb >> 8;
    const float* W = (z == 0) ? Wq : (z == 1) ? Wk : Wv;
    unsigned short* Wt = Wall + (size_t)z * H_ * D_ * C_;
    const int r = tid >> 4, c4 = (tid & 15) * 4;
    #pragma unroll
    for (int p = 0; p < 4; p++) {
        int cl = r + p * 16;
        float4 v = *(const float4*)&W[((size_t)h * C_ + c0 + cl) * D_ + c4];
        t[cl][c4 + 0] = v.x; t[cl][c4 + 1] = v.y;
        t[cl][c4 + 2] = v.z; t[cl][c4 + 3] = v.w;
    }
    __syncthreads();
    #pragma unroll
    for (int p = 0; p < 4; p++) {
        int d = r + p * 16;
        ushort4 o;
        o.x = f2bf(t[c4 + 0][d]); o.y = f2bf(t[c4 + 1][d]);
        o.z = f2bf(t[c4 + 2][d]); o.w = f2bf(t[c4 + 3][d]);
        *(ushort4*)&Wt[((size_t)h * D_ + d) * C_ + c0 + c4] = o;
    }
}

// ---------------------------------------------------------------------------
// QKV GEMM (r8/r10 register-prefetch structure): xb bf16 (4096x1024) x
// Wall^T bf16 (3072x1024), 128x128 tiles. grid = (32, 24).
// z==0 -> Q (scaled 0.125*log2e), z==1 -> K, z==2 -> V^T (B,H,D,T) directly.
// ---------------------------------------------------------------------------
__global__ __launch_bounds__(256) void qkv_big(
    const unsigned short* __restrict__ X,
    const unsigned short* __restrict__ Wall,
    unsigned short* __restrict__ Qo,
    unsigned short* __restrict__ Ko,
    unsigned short* __restrict__ Vt)
{
    __shared__ unsigned short As[128][72];
    __shared__ unsigned short Bs[128][72];

    const int m0 = blockIdx.x * 128;
    const int n0 = blockIdx.y * 128;
    const int z  = n0 >> 10;
    const int tid = threadIdx.x;
    const int w = tid >> 6, lane = tid & 63, quad = lane >> 4, l16 = lane & 15;
    const int wm = w & 1, wn = w >> 1;
    const int lrow = tid >> 3, lcol = (tid & 7) * 8;

    f32x4 acc[4][4] = {};

    short8 ar[4], br[4];
    #pragma unroll
    for (int p = 0; p < 4; p++) {
        int r = lrow + p * 32;
        ar[p] = *(const short8*)&X[(size_t)(m0 + r) * C_ + lcol];
        br[p] = *(const short8*)&Wall[(size_t)(n0 + r) * C_ + lcol];
    }

    for (int k0 = 0; k0 < C_; k0 += 64) {
        __syncthreads();
        #pragma unroll
        for (int p = 0; p < 4; p++) {
            int r = lrow + p * 32;
            *(short8*)&As[r][lcol] = ar[p];
            *(short8*)&Bs[r][lcol] = br[p];
        }
        __syncthreads();
        if (k0 + 64 < C_) {
            #pragma unroll
            for (int p = 0; p < 4; p++) {
                int r = lrow + p * 32;
                ar[p] = *(const short8*)&X[(size_t)(m0 + r) * C_ + k0 + 64 + lcol];
                br[p] = *(const short8*)&Wall[(size_t)(n0 + r) * C_ + k0 + 64 + lcol];
            }
        }
        #pragma unroll
        for (int ks = 0; ks < 2; ks++) {
            short8 af[4], bf[4];
            #pragma unroll
            for (int i = 0; i < 4; i++)
                af[i] = *(const short8*)&As[wm * 64 + i * 16 + l16][ks * 32 + quad * 8];
            #pragma unroll
            for (int j = 0; j < 4; j++)
                bf[j] = *(const short8*)&Bs[wn * 64 + j * 16 + l16][ks * 32 + quad * 8];
            #pragma unroll
            for (int i = 0; i < 4; i++)
                #pragma unroll
                for (int j = 0; j < 4; j++)
                    acc[i][j] = __builtin_amdgcn_mfma_f32_16x16x32_bf16(af[i], bf[j], acc[i][j], 0, 0, 0);
        }
    }

    if (z == 2) {
        // V^T epilogue: Vt[b,h,d,t], 4 consecutive t per (i,j) -> 8B stores
        #pragma unroll
        for (int j = 0; j < 4; j++) {
            const int n = n0 + wn * 64 + j * 16 + l16;
            const int h = (n >> 6) & 15, d = n & 63;
            #pragma unroll
            for (int i = 0; i < 4; i++) {
                const int m = m0 + wm * 64 + i * 16 + quad * 4;
                const int b = m >> 11, t = m & (T_ - 1);
                ushort4 pk;
                pk.x = f2bf(acc[i][j][0]);
                pk.y = f2bf(acc[i][j][1]);
                pk.z = f2bf(acc[i][j][2]);
                pk.w = f2bf(acc[i][j][3]);
                *(ushort4*)&Vt[(((size_t)b * H_ + h) * D_ + d) * T_ + t] = pk;
            }
        }
    } else {
        const float scale = (z == 0) ? 0.125f * LOG2E : 1.0f;
        unsigned short* O = (z == 0) ? Qo : Ko;
        #pragma unroll
        for (int j = 0; j < 4; j++) {
            const int n = n0 + wn * 64 + j * 16 + l16;
            const int h = (n >> 6) & 15, d = n & 63;
            #pragma unroll
            for (int i = 0; i < 4; i++)
                #pragma unroll
                for (int r = 0; r < 4; r++) {
                    const int m = m0 + wm * 64 + i * 16 + quad * 4 + r;
                    const int b = m >> 11, t = m & (T_ - 1);
                    O[(((size_t)b * H_ + h) * T_ + t) * D_ + d] = f2bf(acc[i][j][r] * scale);
                }
        }
    }
}

// ---------------------------------------------------------------------------
// Flash attention (causal), no-max exp2 softmax. r12: shared-staging dual-q.
//  - 512 threads, 8 waves: waves 0-3 own q-tile qb=p, waves 4-7 own qb=31-p
//    (same head). ONE K/V staging per kb feeds BOTH groups -> uniform 33
//    tile-consumptions per block, balance independent of CU assignment.
//  - Group A skips compute for kb > p (still stages + barriers).
//  - XCD remap: 4 whole heads per XCD (2MB K/V < 4MB L2, r11-verified
//    FETCH 123->12MB); sum-to-15 p-pairing decorrelates staging length.
//  - No group-combine: each group owns its 64 output rows outright.
// S' = K*Q^T layout retained: lane holds P at (s=ct*16+quad*4+r, q=wg*16+l16).
// grid = 512 blocks -> 2 blocks/CU, 16 waves/CU, LDS 37.4KB.
// ---------------------------------------------------------------------------
__global__ __launch_bounds__(512, 4) void flash_mfma(
    const unsigned short* __restrict__ Q,
    const unsigned short* __restrict__ K,
    const unsigned short* __restrict__ Vt,   // (B,H,D,T)
    unsigned short* __restrict__ CC)         // (B,T,C)
{
    __shared__ unsigned short kst[64][72];      // K tile [s][d] (shared)
    __shared__ unsigned short vts[64][72];      // V^T tile [d][s] (shared)
    __shared__ unsigned short ps [2][64][72];   // P tile [q][s] per group
    __shared__ float flb[2][64];                // l broadcast per group

    // ---- XCD-contiguous, balance-decorrelated remap (bijective) ----
    const int d    = blockIdx.x;        // 0..511
    const int x    = d & 7;             // xcd slot
    const int loc  = d >> 3;            // 0..63 within xcd chunk
    const int half = loc >> 5, li = loc & 31;
    const int hsub = li & 3, pr = li >> 2;
    const int p    = half ? (15 - pr) : pr;      // 0..15
    const int head = x * 4 + hsub;               // 0..31: 4 heads per xcd
    const int h = head & 15, b = head >> 4;

    const int tid = threadIdx.x;
    const int w = tid >> 6, lane = tid & 63, quad = lane >> 4, l16 = lane & 15;
    const int wg = w & 3;               // wave index within group
    const int g  = w >> 2;              // group: 0 -> qb=p, 1 -> qb=31-p
    const int lrow = tid >> 3, lcol = (tid & 7) * 8;   // 512 thr cover 64x64
    const size_t hb  = ((size_t)b * H_ + h) * T_;
    const size_t hbD = ((size_t)b * H_ + h) * D_;

    const int qb  = g ? (31 - p) : p;
    const int q0  = qb * 64;
    const int myn = qb + 1;             // my group's consumption bound
    const int nkb = 32 - p;             // loop length = max(myn) over groups

    short8 qf[2];
    #pragma unroll
    for (int ks = 0; ks < 2; ks++)
        qf[ks] = *(const short8*)&Q[(hb + q0 + wg * 16 + l16) * D_ + ks * 32 + quad * 8];

    float l_lane = 0.0f;   // l partial for q = wg*16 + l16
    f32x4 o[4] = {};

    short8 kreg, vreg;
    kreg = *(const short8*)&K[(hb + lrow) * D_ + lcol];
    vreg = *(const short8*)&Vt[(hbD + lrow) * T_ + lcol];

    for (int kb = 0; kb < nkb; kb++) {
        __syncthreads();
        *(short8*)&kst[lrow][lcol] = kreg;
        *(short8*)&vts[lrow][lcol] = vreg;
        __syncthreads();
        if (kb + 1 < nkb) {
            const int k0n = (kb + 1) * 64;
            kreg = *(const short8*)&K[(hb + k0n + lrow) * D_ + lcol];
            vreg = *(const short8*)&Vt[(hbD + lrow) * T_ + k0n + lcol];
        }

        if (kb < myn) {
            // S' = K Q^T: lane holds s = ct*16 + quad*4 + r, q = wg*16 + l16
            f32x4 s[4] = {};
            __builtin_amdgcn_s_setprio(1);
            #pragma unroll
            for (int ks = 0; ks < 2; ks++)
                #pragma unroll
                for (int ct = 0; ct < 4; ct++) {
                    short8 kf = *(const short8*)&kst[ct * 16 + l16][ks * 32 + quad * 8];
                    s[ct] = __builtin_amdgcn_mfma_f32_16x16x32_bf16(kf, qf[ks], s[ct], 0, 0, 0);
                }
            __builtin_amdgcn_s_setprio(0);

            if (kb == qb) {   // diagonal block: mask s > q (local indices)
                #pragma unroll
                for (int ct = 0; ct < 4; ct++)
                    #pragma unroll
                    for (int r = 0; r < 4; r++)
                        if (ct * 16 + quad * 4 + r > wg * 16 + l16) s[ct][r] = -INFINITY;
            }

            // P = exp2(S'); pack pairs to bf16 (round-half-up) -> b64 store
            #pragma unroll
            for (int ct = 0; ct < 4; ct++) {
                float e0 = exp2f(s[ct][0]);
                float e1 = exp2f(s[ct][1]);
                float e2 = exp2f(s[ct][2]);
                float e3 = exp2f(s[ct][3]);
                l_lane += (e0 + e1) + (e2 + e3);
                uint2 pk;
                pk.x = __builtin_amdgcn_perm(
                    __float_as_uint(e1) + 0x8000u, __float_as_uint(e0) + 0x8000u, 0x07060302u);
                pk.y = __builtin_amdgcn_perm(
                    __float_as_uint(e3) + 0x8000u, __float_as_uint(e2) + 0x8000u, 0x07060302u);
                *(uint2*)&ps[g][wg * 16 + l16][ct * 16 + quad * 4] = pk;
            }

            // O += P V (ps rows wave-private; same-wave DS ordering, no barrier)
            __builtin_amdgcn_s_setprio(1);
            #pragma unroll
            for (int ks = 0; ks < 2; ks++) {
                short8 pa = *(const short8*)&ps[g][wg * 16 + l16][ks * 32 + quad * 8];
                #pragma unroll
                for (int ct = 0; ct < 4; ct++) {
                    short8 vf = *(const short8*)&vts[ct * 16 + l16][ks * 32 + quad * 8];
                    o[ct] = __builtin_amdgcn_mfma_f32_16x16x32_bf16(pa, vf, o[ct], 0, 0, 0);
                }
            }
            __builtin_amdgcn_s_setprio(0);
        }
    }

    // total l per q: reduce across quads (lanes sharing l16)
    l_lane += __shfl_xor(l_lane, 16);
    l_lane += __shfl_xor(l_lane, 32);
    if (lane < 16) flb[g][wg * 16 + lane] = l_lane;   // wave-private transpose
    #pragma unroll
    for (int r = 0; r < 4; r++) {
        const int q = wg * 16 + quad * 4 + r;
        const float invl = 1.0f / flb[g][q];
        const int t = q0 + q;
        #pragma unroll
        for (int ct = 0; ct < 4; ct++)
            CC[((size_t)b * T_ + t) * C_ + h * D_ + ct * 16 + l16] = f2bf(o[ct][r] * invl);
    }
}

// ---------------------------------------------------------------------------
// Output projection (r8/r10 structure): out[m,n] = sum_c CC[m,c] * Wo[n,c],
// 128x128 tiles, register-prefetched. grid = (32, 8). fp32 output.
// ---------------------------------------------------------------------------
__global__ __launch_bounds__(256) void out_big(
    const unsigned short* __restrict__ X,
    const unsigned short* __restrict__ Wob,
    float* __restrict__ out)
{
    __shared__ unsigned short As[128][72];
    __shared__ unsigned short Bs[128][72];

    const int m0 = blockIdx.x * 128;
    const int n0 = blockIdx.y * 128;
    const int tid = threadIdx.x;
    const int w = tid >> 6, lane = tid & 63, quad = lane >> 4, l16 = lane & 15;
    const int wm = w & 1, wn = w >> 1;
    const int lrow = tid >> 3, lcol = (tid & 7) * 8;

    f32x4 acc[4][4] = {};

    short8 ar[4], br[4];
    #pragma unroll
    for (int p = 0; p < 4; p++) {
        int r = lrow + p * 32;
        ar[p] = *(const short8*)&X[(size_t)(m0 + r) * C_ + lcol];
        br[p] = *(const short8*)&Wob[(size_t)(n0 + r) * C_ + lcol];
    }

    for (int k0 = 0; k0 < C_; k0 += 64) {
        __syncthreads();
        #pragma unroll
        for (int p = 0; p < 4; p++) {
            int r = lrow + p * 32;
            *(short8*)&As[r][lcol] = ar[p];
            *(short8*)&Bs[r][lcol] = br[p];
        }
        __syncthreads();
        if (k0 + 64 < C_) {
            #pragma unroll
            for (int p = 0; p < 4; p++) {
                int r = lrow + p * 32;
                ar[p] = *(const short8*)&X[(size_t)(m0 + r) * C_ + k0 + 64 + lcol];
                br[p] = *(const short8*)&Wob[(size_t)(n0 + r) * C_ + k0 + 64 + lcol];
            }
        }
        #pragma unroll
        for (int ks = 0; ks < 2; ks++) {
            short8 af[4], bf[4];
            #pragma unroll
            for (int i = 0; i < 4; i++)
                af[i] = *(const short8*)&As[wm * 64 + i * 16 + l16][ks * 32 + quad * 8];
            #pragma unroll
            for (int j = 0; j < 4; j++)
                bf[j] = *(const short8*)&Bs[wn * 64 + j * 16 + l16][ks * 32 + quad * 8];
            #pragma unroll
            for (int i = 0; i < 4; i++)
                #pragma unroll
                for (int j = 0; j < 4; j++)
                    acc[i][j] = __builtin_amdgcn_mfma_f32_16x16x32_bf16(af[i], bf[j], acc[i][j], 0, 0, 0);
        }
    }

    #pragma unroll
    for (int i = 0; i < 4; i++)
        #pragma unroll
        for (int j = 0; j < 4; j++)
            #pragma unroll
            for (int r = 0; r < 4; r++)
                out[(size_t)(m0 + wm * 64 + i * 16 + quad * 4 + r) * C_ + n0 + wn * 64 + j * 16 + l16] = acc[i][j][r];
}

extern "C" void kernel_launch(void* const* d_in, const int* in_sizes, int n_in,
                              void* d_out, int out_size, void* d_ws, size_t ws_size,
                              hipStream_t stream) {
    const float* x  = (const float*)d_in[0];
    const float* Wq = (const float*)d_in[1];
    const float* Wk = (const float*)d_in[2];
    const float* Wv = (const float*)d_in[3];
    const float* Wo = (const float*)d_in[4];
    float* out = (float*)d_out;

    const size_t nX = (size_t)B_ * T_ * C_;      // 4M
    const size_t nW = (size_t)H_ * C_ * D_;      // 1M per z
    const size_t nQ = (size_t)B_ * H_ * T_ * D_; // 4M
    unsigned short* xb   = (unsigned short*)d_ws;
    unsigned short* Wall = xb + nX;
    unsigned short* Wob  = Wall + 3 * nW;
    unsigned short* Qb   = Wob + nW;
    unsigned short* Kb   = Qb + nQ;
    unsigned short* Vtb  = Kb + nQ;
    unsigned short* CCb  = Vtb + nQ;   // total 24M ushorts = 48 MB

    prep_all<<<dim3(NCAST + 768), 256, 0, stream>>>(
        x, Wq, Wk, Wv, Wo, xb, Wall, Wob, (int)nX, (int)nW);
    qkv_big<<<dim3(32, 24), 256, 0, stream>>>(xb, Wall, Qb, Kb, Vtb);
    flash_mfma<<<dim3(512), 512, 0, stream>>>(Qb, Kb, Vtb, CCb);
    out_big<<<dim3(32, 8), 256, 0, stream>>>(CCb, Wob, out);
}

// Round 3
// 169.483 us; speedup vs baseline: 1.1586x; 1.0315x over previous
//
#include <hip/hip_runtime.h>
#include <math.h>

#define B_ 2
#define T_ 2048
#define C_ 1024
#define H_ 16
#define D_ 64

typedef short short8 __attribute__((ext_vector_type(8)));
typedef float f32x4 __attribute__((ext_vector_type(4)));
typedef float f32x16 __attribute__((ext_vector_type(16)));

#define LOG2E 1.44269504088896f

__device__ __forceinline__ unsigned short f2bf(float f) {
    unsigned int u = __float_as_uint(f);
    u += 0x7FFFu + ((u >> 16) & 1u);
    return (unsigned short)(u >> 16);
}

#define NCAST 2560   // (4M + 1M) / 2048 cast blocks

// ---------------------------------------------------------------------------
// Fused prep: blocks [0,NCAST) cast x|Wo fp32->bf16 (8 elems/thread);
// blocks [NCAST, NCAST+768) transpose Wq/Wk/Wv (H,C,D)->(H,D,C) bf16 into
// Wall^T slices. [r10 verified]
// ---------------------------------------------------------------------------
__global__ __launch_bounds__(256) void prep_all(
    const float* __restrict__ x,  const float* __restrict__ Wq,
    const float* __restrict__ Wk, const float* __restrict__ Wv,
    const float* __restrict__ Wo,
    unsigned short* __restrict__ xb,   unsigned short* __restrict__ Wall,
    unsigned short* __restrict__ wob,  int nX, int nW)
{
    const int bid = blockIdx.x;
    const int tid = threadIdx.x;
    if (bid < NCAST) {
        int i = (bid * 256 + tid) * 8;
        const float* s;
        unsigned short* d;
        if (i < nX) { s = x + i; d = xb + i; }
        else {
            int j = i - nX;
            if (j >= nW) return;
            s = Wo + j; d = wob + j;
        }
        float4 a = *(const float4*)s;
        float4 b = *(const float4*)(s + 4);
        ushort4 o0, o1;
        o0.x = f2bf(a.x); o0.y = f2bf(a.y); o0.z = f2bf(a.z); o0.w = f2bf(a.w);
        o1.x = f2bf(b.x); o1.y = f2bf(b.y); o1.z = f2bf(b.z); o1.w = f2bf(b.w);
        *(ushort4*)d = o0;
        *(ushort4*)(d + 4) = o1;
        return;
    }
    // transpose path
    __shared__ float t[64][65];
    const int tb = bid - NCAST;          // 0..767
    const int c0 = (tb & 15) * 64;
    const int h  = (tb >> 4) & 15;
    const int z  = tb >> 8;
    const float* W = (z == 0) ? Wq : (z == 1) ? Wk : Wv;
    unsigned short* Wt = Wall + (size_t)z * H_ * D_ * C_;
    const int r = tid >> 4, c4 = (tid & 15) * 4;
    #pragma unroll
    for (int p = 0; p < 4; p++) {
        int cl = r + p * 16;
        float4 v = *(const float4*)&W[((size_t)h * C_ + c0 + cl) * D_ + c4];
        t[cl][c4 + 0] = v.x; t[cl][c4 + 1] = v.y;
        t[cl][c4 + 2] = v.z; t[cl][c4 + 3] = v.w;
    }
    __syncthreads();
    #pragma unroll
    for (int p = 0; p < 4; p++) {
        int d = r + p * 16;
        ushort4 o;
        o.x = f2bf(t[c4 + 0][d]); o.y = f2bf(t[c4 + 1][d]);
        o.z = f2bf(t[c4 + 2][d]); o.w = f2bf(t[c4 + 3][d]);
        *(ushort4*)&Wt[((size_t)h * D_ + d) * C_ + c0 + c4] = o;
    }
}

// ---------------------------------------------------------------------------
// QKV GEMM (r8/r10 register-prefetch structure): xb bf16 (4096x1024) x
// Wall^T bf16 (3072x1024), 128x128 tiles. grid = (32, 24).
// z==0 -> Q (scaled 0.125*log2e), z==1 -> K, z==2 -> V^T (B,H,D,T) directly.
// ---------------------------------------------------------------------------
__global__ __launch_bounds__(256) void qkv_big(
    const unsigned short* __restrict__ X,
    const unsigned short* __restrict__ Wall,
    unsigned short* __restrict__ Qo,
    unsigned short* __restrict__ Ko,
    unsigned short* __restrict__ Vt)
{
    __shared__ unsigned short As[128][72];
    __shared__ unsigned short Bs[128][72];

    const int m0 = blockIdx.x * 128;
    const int n0 = blockIdx.y * 128;
    const int z  = n0 >> 10;
    const int tid = threadIdx.x;
    const int w = tid >> 6, lane = tid & 63, quad = lane >> 4, l16 = lane & 15;
    const int wm = w & 1, wn = w >> 1;
    const int lrow = tid >> 3, lcol = (tid & 7) * 8;

    f32x4 acc[4][4] = {};

    short8 ar[4], br[4];
    #pragma unroll
    for (int p = 0; p < 4; p++) {
        int r = lrow + p * 32;
        ar[p] = *(const short8*)&X[(size_t)(m0 + r) * C_ + lcol];
        br[p] = *(const short8*)&Wall[(size_t)(n0 + r) * C_ + lcol];
    }

    for (int k0 = 0; k0 < C_; k0 += 64) {
        __syncthreads();
        #pragma unroll
        for (int p = 0; p < 4; p++) {
            int r = lrow + p * 32;
            *(short8*)&As[r][lcol] = ar[p];
            *(short8*)&Bs[r][lcol] = br[p];
        }
        __syncthreads();
        if (k0 + 64 < C_) {
            #pragma unroll
            for (int p = 0; p < 4; p++) {
                int r = lrow + p * 32;
                ar[p] = *(const short8*)&X[(size_t)(m0 + r) * C_ + k0 + 64 + lcol];
                br[p] = *(const short8*)&Wall[(size_t)(n0 + r) * C_ + k0 + 64 + lcol];
            }
        }
        #pragma unroll
        for (int ks = 0; ks < 2; ks++) {
            short8 af[4], bf[4];
            #pragma unroll
            for (int i = 0; i < 4; i++)
                af[i] = *(const short8*)&As[wm * 64 + i * 16 + l16][ks * 32 + quad * 8];
            #pragma unroll
            for (int j = 0; j < 4; j++)
                bf[j] = *(const short8*)&Bs[wn * 64 + j * 16 + l16][ks * 32 + quad * 8];
            #pragma unroll
            for (int i = 0; i < 4; i++)
                #pragma unroll
                for (int j = 0; j < 4; j++)
                    acc[i][j] = __builtin_amdgcn_mfma_f32_16x16x32_bf16(af[i], bf[j], acc[i][j], 0, 0, 0);
        }
    }

    if (z == 2) {
        // V^T epilogue: Vt[b,h,d,t], 4 consecutive t per (i,j) -> 8B stores
        #pragma unroll
        for (int j = 0; j < 4; j++) {
            const int n = n0 + wn * 64 + j * 16 + l16;
            const int h = (n >> 6) & 15, d = n & 63;
            #pragma unroll
            for (int i = 0; i < 4; i++) {
                const int m = m0 + wm * 64 + i * 16 + quad * 4;
                const int b = m >> 11, t = m & (T_ - 1);
                ushort4 pk;
                pk.x = f2bf(acc[i][j][0]);
                pk.y = f2bf(acc[i][j][1]);
                pk.z = f2bf(acc[i][j][2]);
                pk.w = f2bf(acc[i][j][3]);
                *(ushort4*)&Vt[(((size_t)b * H_ + h) * D_ + d) * T_ + t] = pk;
            }
        }
    } else {
        const float scale = (z == 0) ? 0.125f * LOG2E : 1.0f;
        unsigned short* O = (z == 0) ? Qo : Ko;
        #pragma unroll
        for (int j = 0; j < 4; j++) {
            const int n = n0 + wn * 64 + j * 16 + l16;
            const int h = (n >> 6) & 15, d = n & 63;
            #pragma unroll
            for (int i = 0; i < 4; i++)
                #pragma unroll
                for (int r = 0; r < 4; r++) {
                    const int m = m0 + wm * 64 + i * 16 + quad * 4 + r;
                    const int b = m >> 11, t = m & (T_ - 1);
                    O[(((size_t)b * H_ + h) * T_ + t) * D_ + d] = f2bf(acc[i][j][r] * scale);
                }
        }
    }
}

// ---------------------------------------------------------------------------
// Flash attention (causal), no-max exp2 softmax. r13: 32x32 MFMA + in-reg P.
//  - Shared-staging dual-q structure kept from r12 (verified balanced):
//    512 thr, group 0 -> qb=p, group 1 -> qb=31-p, one K/V staging feeds both.
//  - QK^T and PV use mfma_f32_32x32x16_bf16: per wave per iter only
//    4 kf + 4 vf ds_read_b128 (vs 16 reads with 16x16x32) -> LDS pipe,
//    the measured top consumer (~57% of CU cycles), cut >2x.
//  - P stays in registers (T12): swapped QK^T gives P at (q=lane&31, s=regs);
//    PV A-frag needs (q=lane&31, s=8*(l>>5)+e) -> pure lane<->lane+32
//    exchange: 4x v_permlane32_swap_b32 per iter. No ps LDS round-trip.
//  - Wave (wg): sw=(wg&1)*32 s-half, qw=(wg>>1)*32 q-half. PV partials over
//    own s-half; combined once via fob LDS at epilogue.
// ---------------------------------------------------------------------------
__global__ __launch_bounds__(512, 4) void flash_mfma(
    const unsigned short* __restrict__ Q,
    const unsigned short* __restrict__ K,
    const unsigned short* __restrict__ Vt,   // (B,H,D,T)
    unsigned short* __restrict__ CC)         // (B,T,C)
{
    __shared__ unsigned short kst[64][72];   // K tile [s][d] (shared)
    __shared__ unsigned short vts[64][72];   // V^T tile [d][s] (shared)
    __shared__ float fob[2][64][68];         // o-partial combine per group
    __shared__ float flb_p[2][64];           // l partial (sw=1 waves)
    __shared__ float flb_t[2][64];           // l total broadcast

    // ---- XCD-contiguous, balance-decorrelated remap (bijective, r12) ----
    const int dd   = blockIdx.x;        // 0..511
    const int xs   = dd & 7;            // xcd slot
    const int loc  = dd >> 3;           // 0..63 within xcd chunk
    const int half = loc >> 5, li = loc & 31;
    const int hsub = li & 3, pr = li >> 2;
    const int p    = half ? (15 - pr) : pr;      // 0..15
    const int head = xs * 4 + hsub;              // 0..31: 4 heads per xcd
    const int h = head & 15, b = head >> 4;

    const int tid = threadIdx.x;
    const int w = tid >> 6, lane = tid & 63;
    const int l31 = lane & 31, hi = lane >> 5;
    const int wg = w & 3;               // wave index within group
    const int g  = w >> 2;              // group: 0 -> qb=p, 1 -> qb=31-p
    const int sw = (wg & 1) * 32;       // this wave's s-half of the K-tile
    const int qw = (wg >> 1) * 32;      // this wave's q-half of the q-tile
    const int lrow = tid >> 3, lcol = (tid & 7) * 8;   // 512 thr cover 64x64
    const size_t hb  = ((size_t)b * H_ + h) * T_;
    const size_t hbD = ((size_t)b * H_ + h) * D_;

    const int qb  = g ? (31 - p) : p;
    const int q0  = qb * 64;
    const int myn = qb + 1;             // my group's consumption bound
    const int nkb = 32 - p;             // shared loop length

    // Q B-frag: lane holds Q[q = q0+qw+l31][k = k4*16 + hi*8 + e]
    short8 qf[4];
    #pragma unroll
    for (int k4 = 0; k4 < 4; k4++)
        qf[k4] = *(const short8*)&Q[(hb + q0 + qw + l31) * D_ + k4 * 16 + hi * 8];

    float l_lane = 0.0f;                // l partial for q = qw + l31 (own s,hi)
    f32x16 o0 = {}, o1 = {};            // PV partials: d-tiles 0..31, 32..63

    short8 kreg, vreg;
    kreg = *(const short8*)&K[(hb + lrow) * D_ + lcol];
    vreg = *(const short8*)&Vt[(hbD + lrow) * T_ + lcol];

    for (int kb = 0; kb < nkb; kb++) {
        __syncthreads();
        *(short8*)&kst[lrow][lcol] = kreg;
        *(short8*)&vts[lrow][lcol] = vreg;
        __syncthreads();
        if (kb + 1 < nkb) {
            const int k0n = (kb + 1) * 64;
            kreg = *(const short8*)&K[(hb + k0n + lrow) * D_ + lcol];
            vreg = *(const short8*)&Vt[(hbD + lrow) * T_ + k0n + lcol];
        }

        if (kb < myn) {
            // S' = K Q^T (32x32 tile): row = s = (reg&3)+8*(reg>>2)+4*hi (+sw),
            // col = q = l31 (+qw)
            f32x16 S = {};
            __builtin_amdgcn_s_setprio(1);
            #pragma unroll
            for (int k4 = 0; k4 < 4; k4++) {
                short8 kf = *(const short8*)&kst[sw + l31][k4 * 16 + hi * 8];
                S = __builtin_amdgcn_mfma_f32_32x32x16_bf16(kf, qf[k4], S, 0, 0, 0);
            }
            __builtin_amdgcn_s_setprio(0);

            if (kb == qb) {   // diagonal block: mask s > q (tile-local)
                #pragma unroll
                for (int reg = 0; reg < 16; reg++) {
                    const int srel = (reg & 3) + 4 * hi + 8 * (reg >> 2);
                    if (sw + srel > qw + l31) S[reg] = -INFINITY;
                }
            }

            // P = exp2(S'); pack bf16 pairs: Wd[2*blk+j] = s_rel pair
            // (8blk+4hi+2j, +1)
            unsigned Wd[8];
            #pragma unroll
            for (int blk = 0; blk < 4; blk++) {
                float e0 = exp2f(S[4 * blk + 0]);
                float e1 = exp2f(S[4 * blk + 1]);
                float e2 = exp2f(S[4 * blk + 2]);
                float e3 = exp2f(S[4 * blk + 3]);
                l_lane += (e0 + e1) + (e2 + e3);
                Wd[2 * blk + 0] = __builtin_amdgcn_perm(
                    __float_as_uint(e1) + 0x8000u, __float_as_uint(e0) + 0x8000u, 0x07060302u);
                Wd[2 * blk + 1] = __builtin_amdgcn_perm(
                    __float_as_uint(e3) + 0x8000u, __float_as_uint(e2) + 0x8000u, 0x07060302u);
            }

            // Redistribute to PV A-frags: swap(lo-blk word, hi-blk word)
            // yields both frag words (lane<32 keeps own, lane>=32 gets partner)
            unsigned a0 = Wd[0], b0 = Wd[2];
            asm("v_permlane32_swap_b32 %0, %1" : "+v"(a0), "+v"(b0));
            unsigned a1 = Wd[1], b1 = Wd[3];
            asm("v_permlane32_swap_b32 %0, %1" : "+v"(a1), "+v"(b1));
            unsigned c0 = Wd[4], d0 = Wd[6];
            asm("v_permlane32_swap_b32 %0, %1" : "+v"(c0), "+v"(d0));
            unsigned c1 = Wd[5], d1 = Wd[7];
            asm("v_permlane32_swap_b32 %0, %1" : "+v"(c1), "+v"(d1));
            union { unsigned u[4]; short8 v; } pw0, pw1;
            pw0.u[0] = a0; pw0.u[1] = a1; pw0.u[2] = b0; pw0.u[3] = b1;  // s_rel 0..15
            pw1.u[0] = c0; pw1.u[1] = c1; pw1.u[2] = d0; pw1.u[3] = d1;  // s_rel 16..31

            // O += P V over own s-half: o[q=l31-row][d-col]
            __builtin_amdgcn_s_setprio(1);
            {
                short8 vf;
                vf = *(const short8*)&vts[l31][sw + hi * 8];
                o0 = __builtin_amdgcn_mfma_f32_32x32x16_bf16(pw0.v, vf, o0, 0, 0, 0);
                vf = *(const short8*)&vts[l31][sw + 16 + hi * 8];
                o0 = __builtin_amdgcn_mfma_f32_32x32x16_bf16(pw1.v, vf, o0, 0, 0, 0);
                vf = *(const short8*)&vts[32 + l31][sw + hi * 8];
                o1 = __builtin_amdgcn_mfma_f32_32x32x16_bf16(pw0.v, vf, o1, 0, 0, 0);
                vf = *(const short8*)&vts[32 + l31][sw + 16 + hi * 8];
                o1 = __builtin_amdgcn_mfma_f32_32x32x16_bf16(pw1.v, vf, o1, 0, 0, 0);
            }
            __builtin_amdgcn_s_setprio(0);
        }
    }

    // combine hi halves of l: lane now has l over its wave's full s-half
    l_lane += __shfl_xor(l_lane, 32);

    // ---- combine s-halves (sw=32 waves write partials; sw=0 finalize) ----
    if (wg & 1) {
        if (lane < 32) flb_p[g][qw + lane] = l_lane;
        #pragma unroll
        for (int reg = 0; reg < 16; reg++) {
            const int qr = (reg & 3) + 4 * hi + 8 * (reg >> 2);
            fob[g][qw + qr][l31]      = o0[reg];
            fob[g][qw + qr][32 + l31] = o1[reg];
        }
    }
    __syncthreads();
    if (!(wg & 1)) {
        const float lt = l_lane + flb_p[g][qw + l31];
        if (lane < 32) flb_t[g][qw + lane] = lt;
        #pragma unroll
        for (int reg = 0; reg < 16; reg++) {
            const int qr = (reg & 3) + 4 * hi + 8 * (reg >> 2);
            const float invl = 1.0f / flb_t[g][qw + qr];
            const float v0 = o0[reg] + fob[g][qw + qr][l31];
            const float v1 = o1[reg] + fob[g][qw + qr][32 + l31];
            const int t = q0 + qw + qr;
            CC[((size_t)b * T_ + t) * C_ + h * D_ + l31]      = f2bf(v0 * invl);
            CC[((size_t)b * T_ + t) * C_ + h * D_ + 32 + l31] = f2bf(v1 * invl);
        }
    }
}

// ---------------------------------------------------------------------------
// Output projection (r8/r10 structure): out[m,n] = sum_c CC[m,c] * Wo[n,c],
// 128x128 tiles, register-prefetched. grid = (32, 8). fp32 output.
// ---------------------------------------------------------------------------
__global__ __launch_bounds__(256) void out_big(
    const unsigned short* __restrict__ X,
    const unsigned short* __restrict__ Wob,
    float* __restrict__ out)
{
    __shared__ unsigned short As[128][72];
    __shared__ unsigned short Bs[128][72];

    const int m0 = blockIdx.x * 128;
    const int n0 = blockIdx.y * 128;
    const int tid = threadIdx.x;
    const int w = tid >> 6, lane = tid & 63, quad = lane >> 4, l16 = lane & 15;
    const int wm = w & 1, wn = w >> 1;
    const int lrow = tid >> 3, lcol = (tid & 7) * 8;

    f32x4 acc[4][4] = {};

    short8 ar[4], br[4];
    #pragma unroll
    for (int p = 0; p < 4; p++) {
        int r = lrow + p * 32;
        ar[p] = *(const short8*)&X[(size_t)(m0 + r) * C_ + lcol];
        br[p] = *(const short8*)&Wob[(size_t)(n0 + r) * C_ + lcol];
    }

    for (int k0 = 0; k0 < C_; k0 += 64) {
        __syncthreads();
        #pragma unroll
        for (int p = 0; p < 4; p++) {
            int r = lrow + p * 32;
            *(short8*)&As[r][lcol] = ar[p];
            *(short8*)&Bs[r][lcol] = br[p];
        }
        __syncthreads();
        if (k0 + 64 < C_) {
            #pragma unroll
            for (int p = 0; p < 4; p++) {
                int r = lrow + p * 32;
                ar[p] = *(const short8*)&X[(size_t)(m0 + r) * C_ + k0 + 64 + lcol];
                br[p] = *(const short8*)&Wob[(size_t)(n0 + r) * C_ + k0 + 64 + lcol];
            }
        }
        #pragma unroll
        for (int ks = 0; ks < 2; ks++) {
            short8 af[4], bf[4];
            #pragma unroll
            for (int i = 0; i < 4; i++)
                af[i] = *(const short8*)&As[wm * 64 + i * 16 + l16][ks * 32 + quad * 8];
            #pragma unroll
            for (int j = 0; j < 4; j++)
                bf[j] = *(const short8*)&Bs[wn * 64 + j * 16 + l16][ks * 32 + quad * 8];
            #pragma unroll
            for (int i = 0; i < 4; i++)
                #pragma unroll
                for (int j = 0; j < 4; j++)
                    acc[i][j] = __builtin_amdgcn_mfma_f32_16x16x32_bf16(af[i], bf[j], acc[i][j], 0, 0, 0);
        }
    }

    #pragma unroll
    for (int i = 0; i < 4; i++)
        #pragma unroll
        for (int j = 0; j < 4; j++)
            #pragma unroll
            for (int r = 0; r < 4; r++)
                out[(size_t)(m0 + wm * 64 + i * 16 + quad * 4 + r) * C_ + n0 + wn * 64 + j * 16 + l16] = acc[i][j][r];
}

extern "C" void kernel_launch(void* const* d_in, const int* in_sizes, int n_in,
                              void* d_out, int out_size, void* d_ws, size_t ws_size,
                              hipStream_t stream) {
    const float* x  = (const float*)d_in[0];
    const float* Wq = (const float*)d_in[1];
    const float* Wk = (const float*)d_in[2];
    const float* Wv = (const float*)d_in[3];
    const float* Wo = (const float*)d_in[4];
    float* out = (float*)d_out;

    const size_t nX = (size_t)B_ * T_ * C_;      // 4M
    const size_t nW = (size_t)H_ * C_ * D_;      // 1M per z
    const size_t nQ = (size_t)B_ * H_ * T_ * D_; // 4M
    unsigned short* xb   = (unsigned short*)d_ws;
    unsigned short* Wall = xb + nX;
    unsigned short* Wob  = Wall + 3 * nW;
    unsigned short* Qb   = Wob + nW;
    unsigned short* Kb   = Qb + nQ;
    unsigned short* Vtb  = Kb + nQ;
    unsigned short* CCb  = Vtb + nQ;   // total 24M ushorts = 48 MB

    prep_all<<<dim3(NCAST + 768), 256, 0, stream>>>(
        x, Wq, Wk, Wv, Wo, xb, Wall, Wob, (int)nX, (int)nW);
    qkv_big<<<dim3(32, 24), 256, 0, stream>>>(xb, Wall, Qb, Kb, Vtb);
    flash_mfma<<<dim3(512), 512, 0, stream>>>(Qb, Kb, Vtb, CCb);
    out_big<<<dim3(32, 8), 256, 0, stream>>>(CCb, Wob, out);
}